// Round 22
// baseline (88.592 us; speedup 1.0000x reference)
//
#include <hip/hip_runtime.h>
#include <hip/hip_bf16.h>
#include <stdint.h>

typedef unsigned short u16;
typedef __bf16 bf16x8 __attribute__((ext_vector_type(8)));
typedef u16 u16x8 __attribute__((ext_vector_type(8)));
typedef u16 u16x4 __attribute__((ext_vector_type(4)));
typedef float f32x4 __attribute__((ext_vector_type(4)));

#define MFMA_16x16x32(a, b, c) __builtin_amdgcn_mfma_f32_16x16x32_bf16((a), (b), (c), 0, 0, 0)

#if __has_builtin(__builtin_amdgcn_exp2f)
#define EXP2F(x) __builtin_amdgcn_exp2f(x)
#else
#define EXP2F(x) exp2f(x)
#endif

// 0.125 (1/sqrt(64)) * log2(e): folded into Q so softmax is p = 2^s.
#define QSCALE_F 0.18033688011112042f

__device__ __forceinline__ u16 f2b(float f) {
  __bf16 h = (__bf16)f;
  return __builtin_bit_cast(u16, h);
}

__device__ __forceinline__ void store_c(u16* C, size_t idx, float v) { C[idx] = f2b(v); }
__device__ __forceinline__ void store_c(float* C, size_t idx, float v) { C[idx] = v; }

// async global->LDS, 16B per lane. LDS dest is wave-uniform base; HW adds lane*16B.
__device__ __forceinline__ void gload16(const void* g, void* l) {
  __builtin_amdgcn_global_load_lds(
      (const __attribute__((address_space(1))) unsigned int*)(uintptr_t)(g),
      (__attribute__((address_space(3))) unsigned int*)(uintptr_t)(l),
      16, 0, 0);
}

// Counted vmcnt wait + scheduler pin (rule #18). Literal-only asm via specialization.
template <int N> __device__ __forceinline__ void wait_vmcnt();
#define DEF_WAITVM(N)                                          \
  template <> __device__ __forceinline__ void wait_vmcnt<N>() { \
    asm volatile("s_waitcnt vmcnt(" #N ")" ::: "memory");       \
    __builtin_amdgcn_sched_barrier(0);                          \
  }
DEF_WAITVM(0) DEF_WAITVM(3) DEF_WAITVM(4) DEF_WAITVM(5) DEF_WAITVM(8)

__device__ __forceinline__ void wait_lgkm0() {
  asm volatile("s_waitcnt lgkmcnt(0)" ::: "memory");
  __builtin_amdgcn_sched_barrier(0);
}

// GEMM tile stage: 16B-granule source XOR (bf16: gi^=row&3, fp32: gi^=row&7);
// LDS dest linear (rule #21), same XOR applied at fragment-read time.
template <typename T, int ROWS>
__device__ __forceinline__ void stage_tile(const T* __restrict__ G, int ldg, int tr, int k0,
                                           T* Ls, int wave, int lane) {
  constexpr int EPL = 16 / sizeof(T);
  constexpr int PCE = 64 * EPL;
  constexpr int CALLS = (ROWS * 32) / (4 * PCE);
#pragma unroll
  for (int ci = 0; ci < CALLS; ci++) {
    const int base = (wave * CALLS + ci) * PCE;
    const int idx0 = base + lane * EPL;
    const int r = idx0 >> 5;
    const int c = idx0 & 31;
    int csw;
    if constexpr (sizeof(T) == 2)
      csw = ((c >> 3) ^ (r & 3)) << 3;
    else
      csw = ((c >> 2) ^ (r & 7)) << 2;
    gload16(G + (size_t)(tr + r) * ldg + k0 + csw, Ls + base);
  }
}
template <typename T, int ROWS>
struct stage_calls {
  static constexpr int value = (ROWS * 32) / (4 * 64 * (16 / (int)sizeof(T)));
};

__device__ __forceinline__ bf16x8 load_frag_sw(const u16* Ls, int row, int g8) {
  const int c = ((g8 >> 3) ^ (row & 3)) << 3;
  return *(const bf16x8*)(Ls + row * 32 + c);
}
__device__ __forceinline__ bf16x8 load_frag_sw(const float* Ls, int row, int g8) {
  const int g2 = g8 >> 2;
  const int c0 = (g2 ^ (row & 7)) << 2;
  const int c1 = ((g2 + 1) ^ (row & 7)) << 2;
  f32x4 lo = *(const f32x4*)(Ls + row * 32 + c0);
  f32x4 hi = *(const f32x4*)(Ls + row * 32 + c1);
  bf16x8 r;
#pragma unroll
  for (int e = 0; e < 4; e++) {
    r[e] = (__bf16)lo[e];
    r[e + 4] = (__bf16)hi[e];
  }
  return r;
}

// C[M,N] = A[M,K] @ B[N,K]^T (+ bias). TMx128 tile, BK=32, 4 waves (2x2 wave grid).
// COUNTED-VMCNT pipeline (T4, m201-style raw barriers); race proof in r15 notes.
template <typename TA, typename TB, typename TC, bool BIAS, bool QSC, int TM>
__global__ __launch_bounds__(256, 2) void gemm_bt(const TA* __restrict__ A,
                                                  const TB* __restrict__ B,
                                                  const float* __restrict__ bias,
                                                  TC* __restrict__ C,
                                                  int M, int N, int K) {
  constexpr int MI = TM >> 5;
  constexpr int NL = stage_calls<TA, TM>::value + stage_calls<TB, 128>::value;
  __shared__ TA As[2][TM * 32];
  __shared__ TB Bs[2][128 * 32];
  const int tid = threadIdx.x;
  const int lane = tid & 63;
  const int wave = tid >> 6;
  const int l15 = lane & 15;
  const int g = lane >> 4;
  const int g8 = g * 8;
  const int cpx = (int)gridDim.x >> 3;
  const int xsl = (int)blockIdx.x & 7;
  const int jj = (int)blockIdx.x >> 3;
  const int tiles_n = N >> 7;
  int tmi, tni;
  const int gm = cpx / tiles_n;
  if (gm * tiles_n == cpx) {  // tm-minor within XCD slot
    tmi = xsl * gm + (jj % gm);
    tni = jj / gm;
  } else {
    const int bid = xsl * cpx + jj;
    tmi = bid / tiles_n;
    tni = bid % tiles_n;
  }
  const int tm = tmi * TM;
  const int tn = tni << 7;
  const int wm = (wave >> 1) * (TM >> 1);
  const int wn = (wave & 1) << 6;

  f32x4 acc[MI][4] = {};

  const int nt = K >> 5;
  stage_tile<TA, TM>(A, K, tm, 0, As[0], wave, lane);
  stage_tile<TB, 128>(B, K, tn, 0, Bs[0], wave, lane);

  for (int t = 0; t < nt; t++) {
    const int cur = t & 1;
    if (t + 1 < nt) {
      stage_tile<TA, TM>(A, K, tm, (t + 1) << 5, As[cur ^ 1], wave, lane);
      stage_tile<TB, 128>(B, K, tn, (t + 1) << 5, Bs[cur ^ 1], wave, lane);
      wait_vmcnt<NL>();  // stage(t) complete (per-wave); NL new stay in flight
    } else {
      wait_vmcnt<0>();   // last tile: no new issue, drain
    }
    __builtin_amdgcn_s_barrier();  // all waves' stage(t) visible
    __builtin_amdgcn_sched_barrier(0);
    bf16x8 af[MI], bfr[4];
#pragma unroll
    for (int i = 0; i < MI; i++) af[i] = load_frag_sw(As[cur], wm + i * 16 + l15, g8);
#pragma unroll
    for (int i = 0; i < 4; i++) bfr[i] = load_frag_sw(Bs[cur], wn + i * 16 + l15, g8);
    wait_lgkm0();                  // my frag reads done (so next stage may overwrite)
    __builtin_amdgcn_s_barrier();  // all waves done reading buf(t)
#pragma unroll
    for (int mi = 0; mi < MI; mi++)
#pragma unroll
      for (int nj = 0; nj < 4; nj++)
        acc[mi][nj] = MFMA_16x16x32(af[mi], bfr[nj], acc[mi][nj]);
  }

  float bv[4], cs[4];
#pragma unroll
  for (int nj = 0; nj < 4; nj++) {
    const int col = tn + wn + nj * 16 + l15;
    bv[nj] = BIAS ? bias[col] : 0.0f;
    cs[nj] = (QSC && col < 1024) ? QSCALE_F : 1.0f;
  }

#pragma unroll
  for (int mi = 0; mi < MI; mi++) {
#pragma unroll
    for (int nj = 0; nj < 4; nj++) {
      const int row = tm + wm + mi * 16 + g * 4;
      const int col = tn + wn + nj * 16 + l15;
#pragma unroll
      for (int r = 0; r < 4; r++)
        store_c(C, (size_t)(row + r) * N + col, (acc[mi][nj][r] + bv[nj]) * cs[nj]);
    }
  }
}

// fp32 -> bf16, 8 elems/thread: x (524288 units), w_qkv (393216), optionally
// w_out (131072, W3 path). All thresholds %256==0 -> block-uniform branches.
__global__ __launch_bounds__(256) void cvt3(const float* __restrict__ x,
                                            const float* __restrict__ wq,
                                            const float* __restrict__ wo,
                                            u16* __restrict__ xb,
                                            u16* __restrict__ wqb,
                                            u16* __restrict__ wob) {
  const int i = blockIdx.x * 256 + threadIdx.x;
  const float* src;
  u16* dst;
  int k;
  if (i < 524288) {
    src = x;
    dst = xb;
    k = i;
  } else if (i < 524288 + 393216) {
    src = wq;
    dst = wqb;
    k = i - 524288;
  } else {
    src = wo;
    dst = wob;
    k = i - (524288 + 393216);
  }
  const f32x4* p = (const f32x4*)src + (size_t)k * 2;
  f32x4 a = p[0], bq = p[1];
  u16x8 r;
#pragma unroll
  for (int e = 0; e < 4; e++) {
    r[e] = f2b(a[e]);
    r[e + 4] = f2b(bq[e]);
  }
  *((u16x8*)dst + k) = r;
}

// fp32 -> bf16 elementwise, 8 elems/thread (w_out pass, post-gemm1 fallback).
__global__ __launch_bounds__(256) void cvt_bf16(const float* __restrict__ in,
                                                u16* __restrict__ out, int n8) {
  const int i = blockIdx.x * 256 + threadIdx.x;
  if (i >= n8) return;
  const f32x4* p = (const f32x4*)in + (size_t)i * 2;
  f32x4 a = p[0], b = p[1];
  u16x8 r;
#pragma unroll
  for (int e = 0; e < 4; e++) {
    r[e] = f2b(a[e]);
    r[e + 4] = f2b(b[e]);
  }
  *((u16x8*)out + i) = r;
}

// elem(row,col) -> row*64 + (col ^ (swz64(row)<<3)); 16B-granule XOR, involution.
__device__ __forceinline__ int swz64(int row) { return ((row >> 3) ^ row) & 7; }

// Flash attention: r21 structure (8 waves/block, 256 q-rows, 1 block/CU,
// KVBLK=128 4-buffer rotation, 8 barriers) + parity-double-buffered Pl.
// In r21 the two compute() halves per iteration share Pl[w]; the odd half's
// P-writes must drain behind the even half's P-reads (same-wave same-address
// LDS ordering). Pl[2] (tile-parity indexed, pb=buf&1) gives the halves
// disjoint P regions -- removes that intra-wave serialization. LDS 128KB
// (Ks[4] 32 + Vs[4] 32 + Pl[2][8] 64), still 1 block/CU. Wave-private both
// ways: zero cross-wave hazard change. Q pre-scaled in GEMM1 so p = 2^s;
// row-sum deferred; pi(key)=(key&15)*4+(key>>4); setprio (T5).
__global__ __launch_bounds__(512) void attn(const u16* __restrict__ qkv,
                                            u16* __restrict__ attout) {
  __shared__ u16 Ks[4][64 * 64];     // [key][hd] swizzled, 4-buffer rotation
  __shared__ u16 Vs[4][64 * 64];     // [hd][pi(key)] swizzled
  __shared__ u16 Pl[2][8][32 * 64];  // per-parity per-wave [q][pi(key)] swizzled
  const int tid = threadIdx.x;
  const int lane = tid & 63;
  const int w = tid >> 6;  // [0,8)
  const int l15 = lane & 15;
  const int g = lane >> 4;
  const int g8 = g * 8;

  // XCD swizzle: each XCD slot owns 8 whole heads (K/V 2MB -> fits 4MB L2).
  const int bid = blockIdx.x;
  const int xs = bid & 7;
  const int j = bid >> 3;            // [0,32)
  const int bh = xs * 8 + (j >> 2);  // [0,64)
  const int qt = j & 3;              // [0,4)
  const int b = bh >> 4;
  const int h = bh & 15;
  const size_t rowbase = (size_t)b * 1024;
  const int qcol = h * 64;

  // Q in registers: rows qr0..qr0+31 for this wave (pre-scaled in GEMM1)
  const int qr0 = qt * 256 + w * 32;
  bf16x8 qf[2][2];
#pragma unroll
  for (int mi = 0; mi < 2; mi++)
#pragma unroll
    for (int ks = 0; ks < 2; ks++)
      qf[mi][ks] =
          *(const bf16x8*)&qkv[(rowbase + qr0 + mi * 16 + l15) * 3072 + qcol + ks * 32 + g8];

  f32x4 o[2][4] = {};
  float l_r[2][4] = {};

  const int vh3 = tid & 7;
  const int vhc = vh3 << 3;
  const int vkey = tid >> 3;  // [0,64)
  bf16x8 vreg[2];             // V for the two in-flight tiles

  auto loadV = [&](int kt, int vr) {
    vreg[vr] = *(const bf16x8*)&qkv[(rowbase + kt * 64 + vkey) * 3072 + 2048 + qcol + vhc];
  };
  auto writeV = [&](int buf, int vr) {
    const int pos = ((vkey & 15) << 2) | (vkey >> 4);  // pi(key)
    const u16* vu = (const u16*)&vreg[vr];
#pragma unroll
    for (int e = 0; e < 8; e++) {
      const int sl = (vh3 ^ e) & 7;  // = swz64(vhc+e)
      Vs[buf][(vhc + e) * 64 + (pos ^ (sl << 3))] = vu[e];
    }
  };
  // K: wave w stages rows [w*8, w*8+8). Linear LDS dest; global chunk pre-XORed
  // so the linear write lands the swizzled layout.
  auto stageK = [&](int buf, int kt) {
    const int row = w * 8 + (lane >> 3);
    const int cc = (lane & 7) ^ swz64(row);
    gload16(&qkv[(rowbase + kt * 64 + row) * 3072 + 1024 + qcol + cc * 8],
            &Ks[buf][w * 512]);
  };

  // One 64-key half: QK^T from Ks[buf], exp2 softmax, P->Pl[buf&1][w], PV with Vs[buf].
  auto compute = [&](int buf) {
    const int pb = buf & 1;  // tile parity alternates -> disjoint P per half
    f32x4 s[2][4] = {};
    __builtin_amdgcn_s_setprio(1);
#pragma unroll
    for (int nj = 0; nj < 4; nj++) {
      const int key = nj * 16 + l15;
      const int sk = swz64(key) << 3;
#pragma unroll
      for (int ks = 0; ks < 2; ks++) {
        const bf16x8 kfr = *(const bf16x8*)&Ks[buf][key * 64 + ((ks * 32 + g8) ^ sk)];
#pragma unroll
        for (int mi = 0; mi < 2; mi++)
          s[mi][nj] = MFMA_16x16x32(qf[mi][ks], kfr, s[mi][nj]);
      }
    }
    __builtin_amdgcn_s_setprio(0);
#pragma unroll
    for (int mi = 0; mi < 2; mi++)
#pragma unroll
      for (int r = 0; r < 4; r++) {
        const float p0 = EXP2F(s[mi][0][r]);
        const float p1 = EXP2F(s[mi][1][r]);
        const float p2 = EXP2F(s[mi][2][r]);
        const float p3 = EXP2F(s[mi][3][r]);
        l_r[mi][r] += (p0 + p1) + (p2 + p3);
        const int row = mi * 16 + g * 4 + r;
        const int sq = swz64(row) << 3;
        u16x4 pk;
        pk[0] = f2b(p0);
        pk[1] = f2b(p1);
        pk[2] = f2b(p2);
        pk[3] = f2b(p3);
        *(u16x4*)&Pl[pb][w][row * 64 + ((l15 << 2) ^ sq)] = pk;
      }
    bf16x8 pf[2][2];
#pragma unroll
    for (int mi = 0; mi < 2; mi++) {
      const int pr = mi * 16 + l15;
      const int sp = swz64(pr) << 3;
#pragma unroll
      for (int ks = 0; ks < 2; ks++)
        pf[mi][ks] = *(const bf16x8*)&Pl[pb][w][pr * 64 + ((ks * 32 + g8) ^ sp)];
    }
    __builtin_amdgcn_s_setprio(1);
#pragma unroll
    for (int nj = 0; nj < 4; nj++) {
      const int hd = nj * 16 + l15;
      const int sv = swz64(hd) << 3;
#pragma unroll
      for (int ks = 0; ks < 2; ks++) {
        const bf16x8 vf = *(const bf16x8*)&Vs[buf][hd * 64 + ((ks * 32 + g8) ^ sv)];
#pragma unroll
        for (int mi = 0; mi < 2; mi++)
          o[mi][nj] = MFMA_16x16x32(pf[mi][ks], vf, o[mi][nj]);
      }
    }
    __builtin_amdgcn_s_setprio(0);
  };

  // prologue: tiles 0,1 into bufs 0,1
  stageK(0, 0);
  stageK(1, 1);
  loadV(0, 0);
  loadV(1, 1);
  writeV(0, 0);
  writeV(1, 1);
  __syncthreads();

  for (int kt2 = 0; kt2 < 8; kt2++) {
    const int t0 = kt2 * 2;
    if (kt2 < 7) {  // prefetch tiles t0+2, t0+3 (their bufs' readers done last iter)
      stageK((t0 + 2) & 3, t0 + 2);
      stageK((t0 + 3) & 3, t0 + 3);
      loadV(t0 + 2, 0);
      loadV(t0 + 3, 1);
    }
    compute(t0 & 3);
    compute((t0 + 1) & 3);
    if (kt2 < 7) {  // late LDS writes: latency hidden under the two halves
      writeV((t0 + 2) & 3, 0);
      writeV((t0 + 3) & 3, 1);
    }
    __syncthreads();  // drains prefetch; guards 4-buffer rotation
  }

  // final row-sum reduce: one tree over the 16 lanes of group g
#pragma unroll
  for (int mi = 0; mi < 2; mi++)
#pragma unroll
    for (int r = 0; r < 4; r++) {
      float v = l_r[mi][r];
#pragma unroll
      for (int d = 1; d < 16; d <<= 1) v += __shfl_xor(v, d, 64);
      l_r[mi][r] = v;
    }

#pragma unroll
  for (int mi = 0; mi < 2; mi++) {
    float inv[4];
#pragma unroll
    for (int r = 0; r < 4; r++) inv[r] = 1.0f / l_r[mi][r];
#pragma unroll
    for (int nj = 0; nj < 4; nj++)
#pragma unroll
      for (int r = 0; r < 4; r++)
        attout[(rowbase + qr0 + mi * 16 + g * 4 + r) * 1024 + qcol + nj * 16 + l15] =
            f2b(o[mi][nj][r] * inv[r]);
  }
}

extern "C" void kernel_launch(void* const* d_in, const int* in_sizes, int n_in,
                              void* d_out, int out_size, void* d_ws, size_t ws_size,
                              hipStream_t stream) {
  const float* x = (const float*)d_in[0];      // (4,1024,1024) fp32
  const float* w_qkv = (const float*)d_in[1];  // (3072,1024) fp32
  const float* w_out = (const float*)d_in[2];  // (1024,1024) fp32
  const float* b_out = (const float*)d_in[3];  // (1024,) fp32
  float* out = (float*)d_out;                  // (4,1024,1024) fp32

  u16* qkv = (u16*)d_ws;                     // 12,582,912 elems
  u16* attout = qkv + 12582912;              // 4,194,304 elems
  const size_t needA = 39845888ull;          // bf16 path, wob overlays wqb
  const size_t needB = needA + 2097152ull;   // + separate wob region

  u16* xb = attout;               // overlay: dead before attn writes attout
  u16* wqb = attout + 4194304;    // 3,145,728 elems

  if (ws_size >= needB) {
    // Fused path: wob in fresh workspace -> all 3 conversions up front (1 launch).
    u16* wob = wqb + 3145728;     // 1,048,576 elems
    cvt3<<<dim3(4096), dim3(256), 0, stream>>>(x, w_qkv, w_out, xb, wqb, wob);
    gemm_bt<u16, u16, u16, false, true, 128><<<dim3(32 * 24), dim3(256), 0, stream>>>(
        xb, wqb, nullptr, qkv, 4096, 3072, 1024);
    attn<<<dim3(256), dim3(512), 0, stream>>>(qkv, attout);
    gemm_bt<u16, u16, float, true, false, 64><<<dim3(64 * 8), dim3(256), 0, stream>>>(
        attout, wob, b_out, out, 4096, 1024, 1024);
  } else if (ws_size >= needA) {
    // r17 path: wob overlays wqb, converted after gemm1.
    u16* wob = wqb;
    cvt3<<<dim3(3584), dim3(256), 0, stream>>>(x, w_qkv, w_qkv, xb, wqb, wob);
    gemm_bt<u16, u16, u16, false, true, 128><<<dim3(32 * 24), dim3(256), 0, stream>>>(
        xb, wqb, nullptr, qkv, 4096, 3072, 1024);
    cvt_bf16<<<dim3(512), dim3(256), 0, stream>>>(w_out, wob, 131072);
    attn<<<dim3(256), dim3(512), 0, stream>>>(qkv, attout);
    gemm_bt<u16, u16, float, true, false, 64><<<dim3(64 * 8), dim3(256), 0, stream>>>(
        attout, wob, b_out, out, 4096, 1024, 1024);
  } else {
    gemm_bt<float, float, u16, false, true, 128><<<dim3(32 * 24), dim3(256), 0, stream>>>(
        x, w_qkv, nullptr, qkv, 4096, 3072, 1024);
    attn<<<dim3(256), dim3(512), 0, stream>>>(qkv, attout);
    gemm_bt<u16, float, float, true, false, 64><<<dim3(64 * 8), dim3(256), 0, stream>>>(
        attout, w_out, b_out, out, 4096, 1024, 1024);
  }
}

// Round 24
// 88.375 us; speedup vs baseline: 1.0025x; 1.0025x over previous
//
#include <hip/hip_runtime.h>
#include <hip/hip_bf16.h>
#include <stdint.h>

typedef unsigned short u16;
typedef __bf16 bf16x8 __attribute__((ext_vector_type(8)));
typedef u16 u16x8 __attribute__((ext_vector_type(8)));
typedef u16 u16x4 __attribute__((ext_vector_type(4)));
typedef float f32x4 __attribute__((ext_vector_type(4)));

#define MFMA_16x16x32(a, b, c) __builtin_amdgcn_mfma_f32_16x16x32_bf16((a), (b), (c), 0, 0, 0)

#if __has_builtin(__builtin_amdgcn_exp2f)
#define EXP2F(x) __builtin_amdgcn_exp2f(x)
#else
#define EXP2F(x) exp2f(x)
#endif

// 0.125 (1/sqrt(64)) * log2(e): folded into Q so softmax is p = 2^s.
#define QSCALE_F 0.18033688011112042f

__device__ __forceinline__ u16 f2b(float f) {
  __bf16 h = (__bf16)f;
  return __builtin_bit_cast(u16, h);
}

__device__ __forceinline__ void store_c(u16* C, size_t idx, float v) { C[idx] = f2b(v); }
__device__ __forceinline__ void store_c(float* C, size_t idx, float v) { C[idx] = v; }

// async global->LDS, 16B per lane. LDS dest is wave-uniform base; HW adds lane*16B.
__device__ __forceinline__ void gload16(const void* g, void* l) {
  __builtin_amdgcn_global_load_lds(
      (const __attribute__((address_space(1))) unsigned int*)(uintptr_t)(g),
      (__attribute__((address_space(3))) unsigned int*)(uintptr_t)(l),
      16, 0, 0);
}

// Counted vmcnt wait + scheduler pin (rule #18). Literal-only asm via specialization.
template <int N> __device__ __forceinline__ void wait_vmcnt();
#define DEF_WAITVM(N)                                          \
  template <> __device__ __forceinline__ void wait_vmcnt<N>() { \
    asm volatile("s_waitcnt vmcnt(" #N ")" ::: "memory");       \
    __builtin_amdgcn_sched_barrier(0);                          \
  }
DEF_WAITVM(0) DEF_WAITVM(4) DEF_WAITVM(5) DEF_WAITVM(6) DEF_WAITVM(8)
DEF_WAITVM(10) DEF_WAITVM(16)

__device__ __forceinline__ void wait_lgkm0() {
  asm volatile("s_waitcnt lgkmcnt(0)" ::: "memory");
  __builtin_amdgcn_sched_barrier(0);
}

// GEMM tile stage: 16B-granule source XOR (bf16: gi^=row&3, fp32: gi^=row&7);
// LDS dest linear (rule #21), same XOR applied at fragment-read time.
template <typename T, int ROWS>
__device__ __forceinline__ void stage_tile(const T* __restrict__ G, int ldg, int tr, int k0,
                                           T* Ls, int wave, int lane) {
  constexpr int EPL = 16 / sizeof(T);
  constexpr int PCE = 64 * EPL;
  constexpr int CALLS = (ROWS * 32) / (4 * PCE);
#pragma unroll
  for (int ci = 0; ci < CALLS; ci++) {
    const int base = (wave * CALLS + ci) * PCE;
    const int idx0 = base + lane * EPL;
    const int r = idx0 >> 5;
    const int c = idx0 & 31;
    int csw;
    if constexpr (sizeof(T) == 2)
      csw = ((c >> 3) ^ (r & 3)) << 3;
    else
      csw = ((c >> 2) ^ (r & 7)) << 2;
    gload16(G + (size_t)(tr + r) * ldg + k0 + csw, Ls + base);
  }
}
template <typename T, int ROWS>
struct stage_calls {
  static constexpr int value = (ROWS * 32) / (4 * 64 * (16 / (int)sizeof(T)));
};

__device__ __forceinline__ bf16x8 load_frag_sw(const u16* Ls, int row, int g8) {
  const int c = ((g8 >> 3) ^ (row & 3)) << 3;
  return *(const bf16x8*)(Ls + row * 32 + c);
}
__device__ __forceinline__ bf16x8 load_frag_sw(const float* Ls, int row, int g8) {
  const int g2 = g8 >> 2;
  const int c0 = (g2 ^ (row & 7)) << 2;
  const int c1 = ((g2 + 1) ^ (row & 7)) << 2;
  f32x4 lo = *(const f32x4*)(Ls + row * 32 + c0);
  f32x4 hi = *(const f32x4*)(Ls + row * 32 + c1);
  bf16x8 r;
#pragma unroll
  for (int e = 0; e < 4; e++) {
    r[e] = (__bf16)lo[e];
    r[e + 4] = (__bf16)hi[e];
  }
  return r;
}

// C[M,N] = A[M,K] @ B[N,K]^T (+ bias). TMx128 tile, BK=32, 4 waves (2x2 wave grid).
// PAIRED counted-vmcnt pipeline (r21's barrier-halving grafted onto the r15 T4
// template): 4-buffer rotation, two K-tiles per barrier set:
//   pair p: stage(t0+2), stage(t0+3) -> vmcnt(2NL) -> bar -> frags(t0)+frags(t0+1)
//           -> lgkmcnt(0) -> bar -> MFMA(t0) + MFMA(t0+1)
// Race proof: vmcnt(2NL) retires all but the 2NL just-issued loads (oldest-first,
// m135) = this pair's operands staged (issued last pair) complete; bar1 makes it
// cross-wave. stage(t0+2) overwrites buf[(t0+2)&3], last read as tile t0-2 in the
// previous pair, whose ds_reads drained at that pair's lgkmcnt(0)+bar2. Final
// pair waits vmcnt(0). Barrier count halves vs r15 (2 per 2 tiles).
template <typename TA, typename TB, typename TC, bool BIAS, bool QSC, int TM>
__global__ __launch_bounds__(256, 2) void gemm_bt(const TA* __restrict__ A,
                                                  const TB* __restrict__ B,
                                                  const float* __restrict__ bias,
                                                  TC* __restrict__ C,
                                                  int M, int N, int K) {
  constexpr int MI = TM >> 5;
  constexpr int NL = stage_calls<TA, TM>::value + stage_calls<TB, 128>::value;
  __shared__ TA As[4][TM * 32];
  __shared__ TB Bs[4][128 * 32];
  const int tid = threadIdx.x;
  const int lane = tid & 63;
  const int wave = tid >> 6;
  const int l15 = lane & 15;
  const int g = lane >> 4;
  const int g8 = g * 8;
  const int cpx = (int)gridDim.x >> 3;
  const int xsl = (int)blockIdx.x & 7;
  const int jj = (int)blockIdx.x >> 3;
  const int tiles_n = N >> 7;
  int tmi, tni;
  const int gm = cpx / tiles_n;
  if (gm * tiles_n == cpx) {  // tm-minor within XCD slot
    tmi = xsl * gm + (jj % gm);
    tni = jj / gm;
  } else {
    const int bid = xsl * cpx + jj;
    tmi = bid / tiles_n;
    tni = bid % tiles_n;
  }
  const int tm = tmi * TM;
  const int tn = tni << 7;
  const int wm = (wave >> 1) * (TM >> 1);
  const int wn = (wave & 1) << 6;

  f32x4 acc[MI][4] = {};

  const int np = K >> 6;  // pairs of 32-wide K-tiles
  stage_tile<TA, TM>(A, K, tm, 0, As[0], wave, lane);
  stage_tile<TB, 128>(B, K, tn, 0, Bs[0], wave, lane);
  stage_tile<TA, TM>(A, K, tm, 32, As[1], wave, lane);
  stage_tile<TB, 128>(B, K, tn, 32, Bs[1], wave, lane);

  for (int p = 0; p < np; p++) {
    const int t0 = p * 2;
    const int bA = t0 & 3;
    const int bB = (t0 + 1) & 3;
    if (p + 1 < np) {
      stage_tile<TA, TM>(A, K, tm, (t0 + 2) << 5, As[(t0 + 2) & 3], wave, lane);
      stage_tile<TB, 128>(B, K, tn, (t0 + 2) << 5, Bs[(t0 + 2) & 3], wave, lane);
      stage_tile<TA, TM>(A, K, tm, (t0 + 3) << 5, As[(t0 + 3) & 3], wave, lane);
      stage_tile<TB, 128>(B, K, tn, (t0 + 3) << 5, Bs[(t0 + 3) & 3], wave, lane);
      wait_vmcnt<2 * NL>();  // this pair's operands complete; 2NL new in flight
    } else {
      wait_vmcnt<0>();       // last pair: drain
    }
    __builtin_amdgcn_s_barrier();  // all waves' stages visible
    __builtin_amdgcn_sched_barrier(0);
    bf16x8 af[2][MI], bfr[2][4];
#pragma unroll
    for (int i = 0; i < MI; i++) {
      af[0][i] = load_frag_sw(As[bA], wm + i * 16 + l15, g8);
      af[1][i] = load_frag_sw(As[bB], wm + i * 16 + l15, g8);
    }
#pragma unroll
    for (int i = 0; i < 4; i++) {
      bfr[0][i] = load_frag_sw(Bs[bA], wn + i * 16 + l15, g8);
      bfr[1][i] = load_frag_sw(Bs[bB], wn + i * 16 + l15, g8);
    }
    wait_lgkm0();                  // my frag reads done (next stage may overwrite)
    __builtin_amdgcn_s_barrier();  // all waves done reading both buffers
#pragma unroll
    for (int h = 0; h < 2; h++)
#pragma unroll
      for (int mi = 0; mi < MI; mi++)
#pragma unroll
        for (int nj = 0; nj < 4; nj++)
          acc[mi][nj] = MFMA_16x16x32(af[h][mi], bfr[h][nj], acc[mi][nj]);
  }

  float bv[4], cs[4];
#pragma unroll
  for (int nj = 0; nj < 4; nj++) {
    const int col = tn + wn + nj * 16 + l15;
    bv[nj] = BIAS ? bias[col] : 0.0f;
    cs[nj] = (QSC && col < 1024) ? QSCALE_F : 1.0f;
  }

#pragma unroll
  for (int mi = 0; mi < MI; mi++) {
#pragma unroll
    for (int nj = 0; nj < 4; nj++) {
      const int row = tm + wm + mi * 16 + g * 4;
      const int col = tn + wn + nj * 16 + l15;
#pragma unroll
      for (int r = 0; r < 4; r++)
        store_c(C, (size_t)(row + r) * N + col, (acc[mi][nj][r] + bv[nj]) * cs[nj]);
    }
  }
}

// fp32 -> bf16, 8 elems/thread: x (524288 units), w_qkv (393216), optionally
// w_out (131072, W3 path). All thresholds %256==0 -> block-uniform branches.
__global__ __launch_bounds__(256) void cvt3(const float* __restrict__ x,
                                            const float* __restrict__ wq,
                                            const float* __restrict__ wo,
                                            u16* __restrict__ xb,
                                            u16* __restrict__ wqb,
                                            u16* __restrict__ wob) {
  const int i = blockIdx.x * 256 + threadIdx.x;
  const float* src;
  u16* dst;
  int k;
  if (i < 524288) {
    src = x;
    dst = xb;
    k = i;
  } else if (i < 524288 + 393216) {
    src = wq;
    dst = wqb;
    k = i - 524288;
  } else {
    src = wo;
    dst = wob;
    k = i - (524288 + 393216);
  }
  const f32x4* p = (const f32x4*)src + (size_t)k * 2;
  f32x4 a = p[0], bq = p[1];
  u16x8 r;
#pragma unroll
  for (int e = 0; e < 4; e++) {
    r[e] = f2b(a[e]);
    r[e + 4] = f2b(bq[e]);
  }
  *((u16x8*)dst + k) = r;
}

// fp32 -> bf16 elementwise, 8 elems/thread (w_out pass, post-gemm1 fallback).
__global__ __launch_bounds__(256) void cvt_bf16(const float* __restrict__ in,
                                                u16* __restrict__ out, int n8) {
  const int i = blockIdx.x * 256 + threadIdx.x;
  if (i >= n8) return;
  const f32x4* p = (const f32x4*)in + (size_t)i * 2;
  f32x4 a = p[0], b = p[1];
  u16x8 r;
#pragma unroll
  for (int e = 0; e < 4; e++) {
    r[e] = f2b(a[e]);
    r[e + 4] = f2b(b[e]);
  }
  *((u16x8*)out + i) = r;
}

// elem(row,col) -> row*64 + (col ^ (swz64(row)<<3)); 16B-granule XOR, involution.
__device__ __forceinline__ int swz64(int row) { return ((row >> 3) ^ row) & 7; }

// Flash attention: r21-EXACT (best measured ~36us; r22's Pl parity split was
// null, reverted). 8 waves/block, 256 q-rows, 1 block/CU, KVBLK=128 4-buffer
// rotation, 8 barriers. K/V staged once per CU per kt. Q pre-scaled in GEMM1 so
// p = 2^s; row-sum deferred; pi(key)=(key&15)*4+(key>>4); setprio (T5).
__global__ __launch_bounds__(512) void attn(const u16* __restrict__ qkv,
                                            u16* __restrict__ attout) {
  __shared__ u16 Ks[4][64 * 64];  // [key][hd] swizzled, 4-buffer rotation
  __shared__ u16 Vs[4][64 * 64];  // [hd][pi(key)] swizzled
  __shared__ u16 Pl[8][32 * 64];  // per-wave [q][pi(key)] swizzled
  const int tid = threadIdx.x;
  const int lane = tid & 63;
  const int w = tid >> 6;  // [0,8)
  const int l15 = lane & 15;
  const int g = lane >> 4;
  const int g8 = g * 8;

  // XCD swizzle: each XCD slot owns 8 whole heads (K/V 2MB -> fits 4MB L2).
  const int bid = blockIdx.x;
  const int xs = bid & 7;
  const int j = bid >> 3;            // [0,32)
  const int bh = xs * 8 + (j >> 2);  // [0,64)
  const int qt = j & 3;              // [0,4)
  const int b = bh >> 4;
  const int h = bh & 15;
  const size_t rowbase = (size_t)b * 1024;
  const int qcol = h * 64;

  // Q in registers: rows qr0..qr0+31 for this wave (pre-scaled in GEMM1)
  const int qr0 = qt * 256 + w * 32;
  bf16x8 qf[2][2];
#pragma unroll
  for (int mi = 0; mi < 2; mi++)
#pragma unroll
    for (int ks = 0; ks < 2; ks++)
      qf[mi][ks] =
          *(const bf16x8*)&qkv[(rowbase + qr0 + mi * 16 + l15) * 3072 + qcol + ks * 32 + g8];

  f32x4 o[2][4] = {};
  float l_r[2][4] = {};

  const int vh3 = tid & 7;
  const int vhc = vh3 << 3;
  const int vkey = tid >> 3;  // [0,64)
  bf16x8 vreg[2];             // V for the two in-flight tiles

  auto loadV = [&](int kt, int vr) {
    vreg[vr] = *(const bf16x8*)&qkv[(rowbase + kt * 64 + vkey) * 3072 + 2048 + qcol + vhc];
  };
  auto writeV = [&](int buf, int vr) {
    const int pos = ((vkey & 15) << 2) | (vkey >> 4);  // pi(key)
    const u16* vu = (const u16*)&vreg[vr];
#pragma unroll
    for (int e = 0; e < 8; e++) {
      const int sl = (vh3 ^ e) & 7;  // = swz64(vhc+e)
      Vs[buf][(vhc + e) * 64 + (pos ^ (sl << 3))] = vu[e];
    }
  };
  // K: wave w stages rows [w*8, w*8+8). Linear LDS dest; global chunk pre-XORed
  // so the linear write lands the swizzled layout.
  auto stageK = [&](int buf, int kt) {
    const int row = w * 8 + (lane >> 3);
    const int cc = (lane & 7) ^ swz64(row);
    gload16(&qkv[(rowbase + kt * 64 + row) * 3072 + 1024 + qcol + cc * 8],
            &Ks[buf][w * 512]);
  };

  // One 64-key half: QK^T from Ks[buf], exp2 softmax, P->Pl[w], PV with Vs[buf].
  auto compute = [&](int buf) {
    f32x4 s[2][4] = {};
    __builtin_amdgcn_s_setprio(1);
#pragma unroll
    for (int nj = 0; nj < 4; nj++) {
      const int key = nj * 16 + l15;
      const int sk = swz64(key) << 3;
#pragma unroll
      for (int ks = 0; ks < 2; ks++) {
        const bf16x8 kfr = *(const bf16x8*)&Ks[buf][key * 64 + ((ks * 32 + g8) ^ sk)];
#pragma unroll
        for (int mi = 0; mi < 2; mi++)
          s[mi][nj] = MFMA_16x16x32(qf[mi][ks], kfr, s[mi][nj]);
      }
    }
    __builtin_amdgcn_s_setprio(0);
#pragma unroll
    for (int mi = 0; mi < 2; mi++)
#pragma unroll
      for (int r = 0; r < 4; r++) {
        const float p0 = EXP2F(s[mi][0][r]);
        const float p1 = EXP2F(s[mi][1][r]);
        const float p2 = EXP2F(s[mi][2][r]);
        const float p3 = EXP2F(s[mi][3][r]);
        l_r[mi][r] += (p0 + p1) + (p2 + p3);
        const int row = mi * 16 + g * 4 + r;
        const int sq = swz64(row) << 3;
        u16x4 pk;
        pk[0] = f2b(p0);
        pk[1] = f2b(p1);
        pk[2] = f2b(p2);
        pk[3] = f2b(p3);
        *(u16x4*)&Pl[w][row * 64 + ((l15 << 2) ^ sq)] = pk;
      }
    bf16x8 pf[2][2];
#pragma unroll
    for (int mi = 0; mi < 2; mi++) {
      const int pr = mi * 16 + l15;
      const int sp = swz64(pr) << 3;
#pragma unroll
      for (int ks = 0; ks < 2; ks++)
        pf[mi][ks] = *(const bf16x8*)&Pl[w][pr * 64 + ((ks * 32 + g8) ^ sp)];
    }
    __builtin_amdgcn_s_setprio(1);
#pragma unroll
    for (int nj = 0; nj < 4; nj++) {
      const int hd = nj * 16 + l15;
      const int sv = swz64(hd) << 3;
#pragma unroll
      for (int ks = 0; ks < 2; ks++) {
        const bf16x8 vf = *(const bf16x8*)&Vs[buf][hd * 64 + ((ks * 32 + g8) ^ sv)];
#pragma unroll
        for (int mi = 0; mi < 2; mi++)
          o[mi][nj] = MFMA_16x16x32(pf[mi][ks], vf, o[mi][nj]);
      }
    }
    __builtin_amdgcn_s_setprio(0);
  };

  // prologue: tiles 0,1 into bufs 0,1
  stageK(0, 0);
  stageK(1, 1);
  loadV(0, 0);
  loadV(1, 1);
  writeV(0, 0);
  writeV(1, 1);
  __syncthreads();

  for (int kt2 = 0; kt2 < 8; kt2++) {
    const int t0 = kt2 * 2;
    if (kt2 < 7) {  // prefetch tiles t0+2, t0+3 (their bufs' readers done last iter)
      stageK((t0 + 2) & 3, t0 + 2);
      stageK((t0 + 3) & 3, t0 + 3);
      loadV(t0 + 2, 0);
      loadV(t0 + 3, 1);
    }
    compute(t0 & 3);
    compute((t0 + 1) & 3);
    if (kt2 < 7) {  // late LDS writes: latency hidden under the two halves
      writeV((t0 + 2) & 3, 0);
      writeV((t0 + 3) & 3, 1);
    }
    __syncthreads();  // drains prefetch; guards 4-buffer rotation
  }

  // final row-sum reduce: one tree over the 16 lanes of group g
#pragma unroll
  for (int mi = 0; mi < 2; mi++)
#pragma unroll
    for (int r = 0; r < 4; r++) {
      float v = l_r[mi][r];
#pragma unroll
      for (int d = 1; d < 16; d <<= 1) v += __shfl_xor(v, d, 64);
      l_r[mi][r] = v;
    }

#pragma unroll
  for (int mi = 0; mi < 2; mi++) {
    float inv[4];
#pragma unroll
    for (int r = 0; r < 4; r++) inv[r] = 1.0f / l_r[mi][r];
#pragma unroll
    for (int nj = 0; nj < 4; nj++)
#pragma unroll
      for (int r = 0; r < 4; r++)
        attout[(rowbase + qr0 + mi * 16 + g * 4 + r) * 1024 + qcol + nj * 16 + l15] =
            f2b(o[mi][nj][r] * inv[r]);
  }
}

extern "C" void kernel_launch(void* const* d_in, const int* in_sizes, int n_in,
                              void* d_out, int out_size, void* d_ws, size_t ws_size,
                              hipStream_t stream) {
  const float* x = (const float*)d_in[0];      // (4,1024,1024) fp32
  const float* w_qkv = (const float*)d_in[1];  // (3072,1024) fp32
  const float* w_out = (const float*)d_in[2];  // (1024,1024) fp32
  const float* b_out = (const float*)d_in[3];  // (1024,) fp32
  float* out = (float*)d_out;                  // (4,1024,1024) fp32

  u16* qkv = (u16*)d_ws;                     // 12,582,912 elems
  u16* attout = qkv + 12582912;              // 4,194,304 elems
  const size_t needA = 39845888ull;          // bf16 path, wob overlays wqb
  const size_t needB = needA + 2097152ull;   // + separate wob region

  u16* xb = attout;               // overlay: dead before attn writes attout
  u16* wqb = attout + 4194304;    // 3,145,728 elems

  if (ws_size >= needB) {
    // Fused path: wob in fresh workspace -> all 3 conversions up front (1 launch).
    u16* wob = wqb + 3145728;     // 1,048,576 elems
    cvt3<<<dim3(4096), dim3(256), 0, stream>>>(x, w_qkv, w_out, xb, wqb, wob);
    gemm_bt<u16, u16, u16, false, true, 128><<<dim3(32 * 24), dim3(256), 0, stream>>>(
        xb, wqb, nullptr, qkv, 4096, 3072, 1024);
    attn<<<dim3(256), dim3(512), 0, stream>>>(qkv, attout);
    gemm_bt<u16, u16, float, true, false, 64><<<dim3(64 * 8), dim3(256), 0, stream>>>(
        attout, wob, b_out, out, 4096, 1024, 1024);
  } else if (ws_size >= needA) {
    // r17 path: wob overlays wqb, converted after gemm1.
    u16* wob = wqb;
    cvt3<<<dim3(3584), dim3(256), 0, stream>>>(x, w_qkv, w_qkv, xb, wqb, wob);
    gemm_bt<u16, u16, u16, false, true, 128><<<dim3(32 * 24), dim3(256), 0, stream>>>(
        xb, wqb, nullptr, qkv, 4096, 3072, 1024);
    cvt_bf16<<<dim3(512), dim3(256), 0, stream>>>(w_out, wob, 131072);
    attn<<<dim3(256), dim3(512), 0, stream>>>(qkv, attout);
    gemm_bt<u16, u16, float, true, false, 64><<<dim3(64 * 8), dim3(256), 0, stream>>>(
        attout, wob, b_out, out, 4096, 1024, 1024);
  } else {
    gemm_bt<float, float, u16, false, true, 128><<<dim3(32 * 24), dim3(256), 0, stream>>>(
        x, w_qkv, nullptr, qkv, 4096, 3072, 1024);
    attn<<<dim3(256), dim3(512), 0, stream>>>(qkv, attout);
    gemm_bt<u16, float, float, true, false, 64><<<dim3(64 * 8), dim3(256), 0, stream>>>(
        attout, w_out, b_out, out, 4096, 1024, 1024);
  }
}